// Round 1
// baseline (4823.373 us; speedup 1.0000x reference)
//
#include <hip/hip_runtime.h>

#define B_ 64
#define C_ 128
#define H_ 36
#define W_ 100
#define K_ 9
#define PAD_ 4
#define KTOT (C_ * K_)       // 1152
#define NCHUNK (KTOT / 32)   // 36
#define LDSTRIDE 136         // padded row stride (elems) to break bank conflicts
#define BLROWS 120           // l-slots: covers l + kw for l<112, kw<=8
#define PASSSZ (8 * NCHUNK * 64 * 8)   // u16 elems of swizzled weights per pass

typedef __attribute__((ext_vector_type(8))) short short8;
typedef __attribute__((ext_vector_type(4))) float f32x4;
typedef unsigned short u16;

__device__ __forceinline__ u16 f2bf(float f) {
    union { float f; unsigned u; } v; v.f = f;
    unsigned u = v.u;
    return (u16)((u + 0x7fffu + ((u >> 16) & 1u)) >> 16);
}

// Pre-swizzle weights into MFMA A-fragment order (bf16):
// afrag[((p*8+ct)*36+kk)*64 + lane][j] = W_p[co=ct*16+(lane&15)][ci][kw]
// where k = kk*32 + (lane>>4)*8 + j, kw = k>>7, ci = k&127  (K-order: kw outer, ci inner)
__global__ void prep_kernel(const float* __restrict__ wd, const float* __restrict__ wu,
                            const float* __restrict__ wr, const float* __restrict__ wl,
                            u16* __restrict__ afrag) {
    const int bid = blockIdx.x;             // p*288 + ct*36 + kk
    const int p = bid / (8 * NCHUNK);
    const int rem = bid % (8 * NCHUNK);
    const int ct = rem / NCHUNK;
    const int kk = rem % NCHUNK;
    const float* w = (p == 0) ? wd : (p == 1) ? wu : (p == 2) ? wr : wl;
    const int lane = threadIdx.x;
    const int co = ct * 16 + (lane & 15);
    const int k0 = kk * 32 + ((lane >> 4) << 3);
    u16 v[8];
#pragma unroll
    for (int j = 0; j < 8; ++j) {
        const int k = k0 + j;
        const int kw = k >> 7;
        const int ci = k & 127;
        v[j] = f2bf(w[(co * C_ + ci) * K_ + kw]);
    }
    u16* dst = afrag + ((size_t)(bid * 64 + lane)) * 8;
#pragma unroll
    for (int j = 0; j < 8; ++j) dst[j] = v[j];
}

template <int AXIS>
__device__ __forceinline__ void run_pass(const float* __restrict__ sread,
                                         float* __restrict__ fb,
                                         const u16* __restrict__ afr,
                                         const float* __restrict__ bias,
                                         const int nsteps, const int start, const int dir,
                                         const int stage_t,
                                         u16 (*rowT)[BLROWS][LDSTRIDE]) {
    constexpr int L = (AXIS == 0) ? W_ : H_;
    constexpr int NLT = (L + 15) >> 4;      // 7 (H-pass) or 3 (W-pass)
    const int tid = threadIdx.x;
    const int lane = tid & 63;
    const int wv = tid >> 6;
    const int cg = wv & 3, lg = wv >> 2;
    const int q = lane >> 4, r = lane & 15;
    const int lt0 = lg, lt1 = lg + 4;
    const bool has0 = (lt0 < NLT);
    const bool has1 = (lt1 < NLT);
    const int ct0 = cg * 2, ct1 = ct0 + 1;

    // ---- stage initial carry slice from field into buffer 0 ----
    for (int e = tid; e < C_ * L; e += 1024) {
        const int c = e / L, l = e - c * L;
        const int fi = (AXIS == 0) ? (c * H_ + stage_t) * W_ + l
                                   : (c * H_ + l) * W_ + stage_t;
        rowT[0][l + PAD_][c] = f2bf(fb[fi]);
    }
    __syncthreads();

    const u16* a0p = afr + ((size_t)(ct0 * NCHUNK) * 64 + lane) * 8;
    const u16* a1p = afr + ((size_t)(ct1 * NCHUNK) * 64 + lane) * 8;

    for (int s = 1; s <= nsteps; ++s) {
        const int cur = (s - 1) & 1, nxt = s & 1;
        const int t = start + dir * s;

        f32x4 acc00 = {0.f, 0.f, 0.f, 0.f};
        f32x4 acc01 = {0.f, 0.f, 0.f, 0.f};
        f32x4 acc10 = {0.f, 0.f, 0.f, 0.f};
        f32x4 acc11 = {0.f, 0.f, 0.f, 0.f};

        if (has1) {
#pragma unroll 2
            for (int kk = 0; kk < NCHUNK; ++kk) {
                const int kw = kk >> 2;
                const int cib = ((kk & 3) << 5) | (q << 3);
                const short8 av0 = *(const short8*)(a0p + (size_t)kk * 512);
                const short8 av1 = *(const short8*)(a1p + (size_t)kk * 512);
                const short8 bv0 = *(const short8*)&rowT[cur][lt0 * 16 + r + kw][cib];
                const short8 bv1 = *(const short8*)&rowT[cur][lt1 * 16 + r + kw][cib];
                acc00 = __builtin_amdgcn_mfma_f32_16x16x32_bf16(av0, bv0, acc00, 0, 0, 0);
                acc10 = __builtin_amdgcn_mfma_f32_16x16x32_bf16(av1, bv0, acc10, 0, 0, 0);
                acc01 = __builtin_amdgcn_mfma_f32_16x16x32_bf16(av0, bv1, acc01, 0, 0, 0);
                acc11 = __builtin_amdgcn_mfma_f32_16x16x32_bf16(av1, bv1, acc11, 0, 0, 0);
            }
        } else if (has0) {
#pragma unroll 2
            for (int kk = 0; kk < NCHUNK; ++kk) {
                const int kw = kk >> 2;
                const int cib = ((kk & 3) << 5) | (q << 3);
                const short8 av0 = *(const short8*)(a0p + (size_t)kk * 512);
                const short8 av1 = *(const short8*)(a1p + (size_t)kk * 512);
                const short8 bv0 = *(const short8*)&rowT[cur][lt0 * 16 + r + kw][cib];
                acc00 = __builtin_amdgcn_mfma_f32_16x16x32_bf16(av0, bv0, acc00, 0, 0, 0);
                acc10 = __builtin_amdgcn_mfma_f32_16x16x32_bf16(av1, bv0, acc10, 0, 0, 0);
            }
        }

        // ---- epilogue: new = s + relu(conv + bias); write field (fp32) + next LDS row (bf16) ----
        auto epi = [&](int ct, int lt, const f32x4& a) {
            const int l = lt * 16 + r;
            if (l >= L) return;
            const int cobase = ct * 16 + (q << 2);
            union { u16 s4[4]; unsigned long long v; } pk;
#pragma unroll
            for (int j = 0; j < 4; ++j) {
                const int co = cobase + j;
                float conv = a[j] + bias[co];
                conv = fmaxf(conv, 0.0f);
                const int fi = (AXIS == 0) ? (co * H_ + t) * W_ + l
                                           : (co * H_ + l) * W_ + t;
                const float nv = sread[fi] + conv;
                fb[fi] = nv;
                pk.s4[j] = f2bf(nv);
            }
            *(unsigned long long*)&rowT[nxt][l + PAD_][cobase] = pk.v;
        };
        if (has0) { epi(ct0, lt0, acc00); epi(ct1, lt0, acc10); }
        if (has1) { epi(ct0, lt1, acc01); epi(ct1, lt1, acc11); }
        __syncthreads();
    }
}

__global__ __launch_bounds__(1024) void spatial_kernel(
    const float* __restrict__ x, float* __restrict__ field,
    const u16* __restrict__ afrag,
    const float* __restrict__ bd, const float* __restrict__ bu,
    const float* __restrict__ br, const float* __restrict__ bl) {
    __shared__ __align__(16) u16 rowT[2][BLROWS][LDSTRIDE];
    const int b = blockIdx.x;
    const int tid = threadIdx.x;
    const float* xb = x + (size_t)b * C_ * H_ * W_;
    float* fb = field + (size_t)b * C_ * H_ * W_;

    // init: field row h=0 = x (never written by H-passes but read by W-passes)
    for (int e = tid; e < C_ * W_; e += 1024) {
        const int c = e / W_, l = e - c * W_;
        fb[c * (H_ * W_) + l] = xb[c * (H_ * W_) + l];
    }
    // zero LDS buffers (halo slots must be 0 for conv zero-padding)
    {
        u16* p = &rowT[0][0][0];
        for (int off = tid * 8; off < 2 * BLROWS * LDSTRIDE; off += 1024 * 8) {
            *(uint4*)(p + off) = make_uint4(0u, 0u, 0u, 0u);
        }
    }
    __syncthreads();

    // down: h = 1..35, carry h-1, s from x
    run_pass<0>(xb, fb, afrag + (size_t)0 * PASSSZ, bd, 35, 0, +1, 0, rowT);
    // up: h = 34..1, carry h+1, s from field (down results)
    run_pass<0>(fb, fb, afrag + (size_t)1 * PASSSZ, bu, 34, 35, -1, 35, rowT);

    // re-zero buffers (H-pass left stale data in slots >= 40 which W-pass reads as halo)
    {
        u16* p = &rowT[0][0][0];
        for (int off = tid * 8; off < 2 * BLROWS * LDSTRIDE; off += 1024 * 8) {
            *(uint4*)(p + off) = make_uint4(0u, 0u, 0u, 0u);
        }
    }
    __syncthreads();

    // right: w = 1..99
    run_pass<1>(fb, fb, afrag + (size_t)2 * PASSSZ, br, 99, 0, +1, 0, rowT);
    // left: w = 98..1
    run_pass<1>(fb, fb, afrag + (size_t)3 * PASSSZ, bl, 98, 99, -1, 99, rowT);
}

extern "C" void kernel_launch(void* const* d_in, const int* in_sizes, int n_in,
                              void* d_out, int out_size, void* d_ws, size_t ws_size,
                              hipStream_t stream) {
    const float* x  = (const float*)d_in[0];
    const float* wd = (const float*)d_in[1];
    const float* bd = (const float*)d_in[2];
    const float* wu = (const float*)d_in[3];
    const float* bu = (const float*)d_in[4];
    const float* wr = (const float*)d_in[5];
    const float* br = (const float*)d_in[6];
    const float* wl = (const float*)d_in[7];
    const float* bl = (const float*)d_in[8];
    u16* afrag = (u16*)d_ws;   // 4 * 294912 B = 1.18 MB of scratch

    prep_kernel<<<dim3(4 * 8 * NCHUNK), dim3(64), 0, stream>>>(wd, wu, wr, wl, afrag);
    spatial_kernel<<<dim3(B_), dim3(1024), 0, stream>>>(
        x, (float*)d_out, afrag, bd, bu, br, bl);
}

// Round 2
// 4509.464 us; speedup vs baseline: 1.0696x; 1.0696x over previous
//
#include <hip/hip_runtime.h>

#define B_ 64
#define C_ 128
#define H_ 36
#define W_ 100
#define K_ 9
#define PAD_ 4
#define NCHUNK 36            // K = 1152 = 36 chunks of 32
#define LDSTRIDE 136         // padded LDS row stride (u16 elems)
#define BLROWS 120
#define PASSSZ (8 * NCHUNK * 64 * 8)   // u16 elems of swizzled weights per pass
#define XQPAR (100 * 128)              // exchange buffer: one parity plane (u16 elems)

typedef __attribute__((ext_vector_type(8))) short short8;
typedef __attribute__((ext_vector_type(4))) float f32x4;
typedef unsigned short u16;

__device__ __forceinline__ u16 f2bf(float f) {
    union { float f; unsigned u; } v; v.f = f;
    unsigned u = v.u;
    return (u16)((u + 0x7fffu + ((u >> 16) & 1u)) >> 16);
}

__global__ void init_flags(int* flags) { flags[threadIdx.x] = 0; }

// Pre-swizzle weights into MFMA A-fragment order (bf16), K-order (kw outer, ci inner)
__global__ void prep_kernel(const float* __restrict__ wd, const float* __restrict__ wu,
                            const float* __restrict__ wr, const float* __restrict__ wl,
                            u16* __restrict__ afrag) {
    const int bid = blockIdx.x;             // p*288 + ct*36 + kk
    const int p = bid / (8 * NCHUNK);
    const int rem = bid % (8 * NCHUNK);
    const int ct = rem / NCHUNK;
    const int kk = rem % NCHUNK;
    const float* w = (p == 0) ? wd : (p == 1) ? wu : (p == 2) ? wr : wl;
    const int lane = threadIdx.x;
    const int co = ct * 16 + (lane & 15);
    const int k0 = kk * 32 + ((lane >> 4) << 3);
    u16 v[8];
#pragma unroll
    for (int j = 0; j < 8; ++j) {
        const int k = k0 + j;
        const int kw = k >> 7;
        const int ci = k & 127;
        v[j] = f2bf(w[(co * C_ + ci) * K_ + kw]);
    }
    u16* dst = afrag + ((size_t)(bid * 64 + lane)) * 8;
#pragma unroll
    for (int j = 0; j < 8; ++j) dst[j] = v[j];
}

template <int AXIS>
__device__ __forceinline__ void run_pass(
    const float* __restrict__ stbase,      // source for initial carry staging
    const float* __restrict__ sread,       // per-step skip-connection source
    float* __restrict__ fb,                // field (output), fp32
    const u16* __restrict__ afr,           // this pass's swizzled weights
    const float* __restrict__ bias,
    const int nsteps, const int start, const int dir, const int stage_t,
    u16 (*rowT)[BLROWS][LDSTRIDE],
    u16* __restrict__ xqb, int* __restrict__ flags4,
    const int p, int& gstep)
{
    constexpr int L = (AXIS == 0) ? W_ : H_;
    const int tid = threadIdx.x;
    const int lane = tid & 63;
    const int wv = tid >> 6;               // 0..7
    const int ctl = wv & 1;                // which of the block's 2 co-tiles
    const int lg = wv >> 1;                // 0..3 l-group
    const int q = lane >> 4, r = lane & 15;
    const int ct_g = 2 * p + ctl;          // global co-tile 0..7
    const bool act0 = (AXIS == 0) || (lg < 3);
    const bool has1 = (AXIS == 0) && (lg < 3);   // second l-tile (lt = lg+4 < 7)
    const int l0 = lg * 16 + r;            // <= 63
    const int l1 = l0 + 64;                // 64..111 (H-pass only)
    const int cobase = ct_g * 16 + (q << 2);

    // ---- weights for this wave's co-tile: register-resident for the pass ----
    short8 areg[NCHUNK];
    {
        const u16* ap = afr + ((size_t)(ct_g * NCHUNK) * 64 + lane) * 8;
#pragma unroll
        for (int kk = 0; kk < NCHUNK; ++kk)
            areg[kk] = *(const short8*)(ap + (size_t)kk * 512);
    }
    float bias_r[4];
#pragma unroll
    for (int j = 0; j < 4; ++j) bias_r[j] = bias[cobase + j];

    // ---- stage initial carry row (full 128 ch) into buffer 0 ----
    for (int e = tid; e < C_ * L; e += 512) {
        const int c = e / L, l = e - c * L;
        const int fi = (AXIS == 0) ? (c * H_ + stage_t) * W_ + l
                                   : (c * H_ + l) * W_ + stage_t;
        rowT[0][l + PAD_][c] = f2bf(stbase[fi]);
    }
    __syncthreads();

    for (int s = 1; s <= nsteps; ++s) {
        ++gstep;
        const int cur = (s - 1) & 1, nxt = s & 1;
        const int t = start + dir * s;

        // prefetch skip-connection values (hide global latency under MFMA)
        float sv0[4], sv1[4];
        if (act0) {
#pragma unroll
            for (int j = 0; j < 4; ++j) {
                const int co = cobase + j;
                const int fi = (AXIS == 0) ? (co * H_ + t) * W_ + l0
                                           : (co * H_ + l0) * W_ + t;
                sv0[j] = sread[fi];        // l0 <= 63 < L always in-range for H; guarded by act0 for W (l0<48, but only l<36 used)
            }
        }
        if (has1 && l1 < L) {
#pragma unroll
            for (int j = 0; j < 4; ++j) {
                const int co = cobase + j;
                const int fi = (co * H_ + t) * W_ + l1;
                sv1[j] = sread[fi];
            }
        }

        f32x4 acc0 = {0.f, 0.f, 0.f, 0.f};
        f32x4 acc1 = {0.f, 0.f, 0.f, 0.f};
        if (act0) {
#pragma unroll
            for (int kk = 0; kk < NCHUNK; ++kk) {
                const int kw = kk >> 2;
                const int cib = ((kk & 3) << 5) | (q << 3);
                const short8 bv0 = *(const short8*)&rowT[cur][l0 + kw][cib];
                acc0 = __builtin_amdgcn_mfma_f32_16x16x32_bf16(areg[kk], bv0, acc0, 0, 0, 0);
                if (has1) {
                    const short8 bv1 = *(const short8*)&rowT[cur][l1 + kw][cib];
                    acc1 = __builtin_amdgcn_mfma_f32_16x16x32_bf16(areg[kk], bv1, acc1, 0, 0, 0);
                }
            }
        }

        const int par = gstep & 1;
        u16* xrow = xqb + (size_t)par * XQPAR;

        auto epi = [&](int l, const f32x4& a, const float* sv) {
            if (l >= L) return;
            union { u16 s4[4]; unsigned long long v; } pk;
#pragma unroll
            for (int j = 0; j < 4; ++j) {
                const float conv = fmaxf(a[j] + bias_r[j], 0.0f);
                const int co = cobase + j;
                const int fi = (AXIS == 0) ? (co * H_ + t) * W_ + l
                                           : (co * H_ + l) * W_ + t;
                const float nv = sv[j] + conv;
                fb[fi] = nv;
                pk.s4[j] = f2bf(nv);
            }
            *(unsigned long long*)(xrow + (size_t)l * C_ + cobase) = pk.v;
        };
        if (act0) epi(l0, acc0, sv0);
        if (has1) epi(l1, acc1, sv1);

        // ---- publish own slice, wait for siblings, rebuild LDS row ----
        __syncthreads();   // drains vmcnt -> all block stores in L2
        if (tid == 0)
            __hip_atomic_store(flags4 + p, gstep, __ATOMIC_RELEASE, __HIP_MEMORY_SCOPE_AGENT);
        if (wv == 0) {
            if (lane < 4) {
                while (__hip_atomic_load(flags4 + lane, __ATOMIC_RELAXED,
                                         __HIP_MEMORY_SCOPE_AGENT) < gstep)
                    __builtin_amdgcn_s_sleep(2);
            }
            __builtin_amdgcn_fence(__ATOMIC_ACQUIRE, "agent");
        }
        __syncthreads();

        for (int i = tid; i < L * 16; i += 512) {
            const int l = i >> 4, sg = (i & 15) << 3;
            *(uint4*)&rowT[nxt][l + PAD_][sg] = *(const uint4*)(xrow + (size_t)l * C_ + sg);
        }
        __syncthreads();
    }
}

__global__ __launch_bounds__(512, 2) void spatial_kernel(
    const float* __restrict__ x, float* __restrict__ field,
    const u16* __restrict__ afrag, u16* __restrict__ xq, int* __restrict__ flags,
    const float* __restrict__ bd, const float* __restrict__ bu,
    const float* __restrict__ br, const float* __restrict__ bl) {
    __shared__ __align__(16) u16 rowT[2][BLROWS][LDSTRIDE];
    const int b = blockIdx.x & 63;         // siblings {b, b+64, b+128, b+192} -> same XCD (%8 heuristic)
    const int p = blockIdx.x >> 6;         // co-piece 0..3 (channels 32p..32p+31)
    const int tid = threadIdx.x;
    const float* xb = x + (size_t)b * C_ * H_ * W_;
    float* fb = field + (size_t)b * C_ * H_ * W_;
    u16* xqb = xq + (size_t)b * 2 * XQPAR;
    int* flags4 = flags + b * 4;
    int gstep = 0;

    // own co-slice of field row h=0 (= x); needed by W-passes
    for (int e = tid; e < 32 * W_; e += 512) {
        const int cl = e / W_, w = e - cl * W_;
        const int co = 32 * p + cl;
        fb[(co * H_) * W_ + w] = xb[(co * H_) * W_ + w];
    }
    // zero LDS (halo rows must be 0)
    {
        u16* pz = &rowT[0][0][0];
        for (int off = tid * 8; off < 2 * BLROWS * LDSTRIDE; off += 512 * 8)
            *(uint4*)(pz + off) = make_uint4(0u, 0u, 0u, 0u);
    }
    __syncthreads();

    // down: h = 1..35 (stage from x row 0; skip source = x)
    run_pass<0>(xb, xb, fb, afrag + (size_t)0 * PASSSZ, bd, 35, 0, +1, 0, rowT, xqb, flags4, p, gstep);
    // up: h = 34..1 (stage from field row 35)
    run_pass<0>(fb, fb, fb, afrag + (size_t)1 * PASSSZ, bu, 34, 35, -1, 35, rowT, xqb, flags4, p, gstep);

    // re-zero LDS (H-pass left nonzero rows beyond W-pass halo)
    {
        u16* pz = &rowT[0][0][0];
        for (int off = tid * 8; off < 2 * BLROWS * LDSTRIDE; off += 512 * 8)
            *(uint4*)(pz + off) = make_uint4(0u, 0u, 0u, 0u);
    }
    __syncthreads();

    // right: w = 1..99
    run_pass<1>(fb, fb, fb, afrag + (size_t)2 * PASSSZ, br, 99, 0, +1, 0, rowT, xqb, flags4, p, gstep);
    // left: w = 98..1
    run_pass<1>(fb, fb, fb, afrag + (size_t)3 * PASSSZ, bl, 98, 99, -1, 99, rowT, xqb, flags4, p, gstep);
}

extern "C" void kernel_launch(void* const* d_in, const int* in_sizes, int n_in,
                              void* d_out, int out_size, void* d_ws, size_t ws_size,
                              hipStream_t stream) {
    const float* x  = (const float*)d_in[0];
    const float* wd = (const float*)d_in[1];
    const float* bd = (const float*)d_in[2];
    const float* wu = (const float*)d_in[3];
    const float* bu = (const float*)d_in[4];
    const float* wr = (const float*)d_in[5];
    const float* br = (const float*)d_in[6];
    const float* wl = (const float*)d_in[7];
    const float* bl = (const float*)d_in[8];

    // ws layout: [0,1KB) flags(256 int) | [1KB, +1.18MB) afrag | xq (3.28 MB)
    int* flags = (int*)d_ws;
    u16* afrag = (u16*)((char*)d_ws + 1024);
    u16* xq    = (u16*)((char*)d_ws + 1024 + (size_t)4 * PASSSZ * 2);

    init_flags<<<dim3(1), dim3(256), 0, stream>>>(flags);
    prep_kernel<<<dim3(4 * 8 * NCHUNK), dim3(64), 0, stream>>>(wd, wu, wr, wl, afrag);
    spatial_kernel<<<dim3(256), dim3(512), 0, stream>>>(
        x, (float*)d_out, afrag, xq, flags, bd, bu, br, bl);
}